// Round 9
// baseline (290.799 us; speedup 1.0000x reference)
//
#include <hip/hip_runtime.h>
#include <hip/hip_bf16.h>

// RGCN layer: out = relu(x @ W_self^T + b + agg/deg)
// Pipeline v9 (7 dispatches):
//   1. prep: xb = bf16(x), A[:,1024:1152] = bf16(x), Bt = bf16([W_rel; W_self^T]),
//      zero hist (block-range split)
//   2. hist: per-dst edge counts (50k bins, atomics)
//   3. scan1: per-1024-chunk sums -> bsum
//   4. scan3: block-local reduce of bsum prefix + chunk exclusive scan -> offsets/cursor
//   5. reorder: sorted[pos] = src | rel<<28
//   6. aggregate: one wave per node; SCALAR edge stream, 16 gathers in flight
//   7. gemm: 128x128 tile m97-style, out = relu(A @ Bt^T + b)

#define D 128
#define RNUM 8
#define KREL (RNUM * D)      // 1024
#define KTOT (KREL + D)      // 1152
#define BLK_M 128

typedef short short8 __attribute__((ext_vector_type(8)));
typedef float float4v __attribute__((ext_vector_type(4)));

// fp32 -> bf16 round-nearest-even (bit pattern)
static __device__ __forceinline__ unsigned int f2b(float f) {
    unsigned int u = __float_as_uint(f);
    return (u + 0x7fffu + ((u >> 16) & 1u)) >> 16;
}
static __device__ __forceinline__ float b2f_lo(unsigned int u) {
    return __uint_as_float(u << 16);
}
static __device__ __forceinline__ float b2f_hi(unsigned int u) {
    return __uint_as_float(u & 0xffff0000u);
}

static __device__ __forceinline__ void gl_lds16(const void* g, void* l) {
    __builtin_amdgcn_global_load_lds(
        (const __attribute__((address_space(1))) unsigned int*)g,
        (__attribute__((address_space(3))) unsigned int*)l, 16, 0, 0);
}

// ---------- prep (3 block ranges): xb + A-self | Bt | hist zero ----------
__global__ void prep_kernel(const float* __restrict__ x,
                            const float* __restrict__ W_rel,
                            const float* __restrict__ W_self,
                            unsigned short* __restrict__ xb,
                            unsigned short* __restrict__ A,
                            unsigned short* __restrict__ Bt,
                            int* __restrict__ hist,
                            int Nn, int xb_blocks, int bt_blocks) {
    if (blockIdx.x < (unsigned)xb_blocks) {
        int t = blockIdx.x * 256 + threadIdx.x;
        int n = t >> 5;              // 32 threads/row, 4 cols each
        int c = (t & 31) * 4;
        if (n >= Nn) return;
        float4 v = *(const float4*)(x + (size_t)n * D + c);
        unsigned int p0 = f2b(v.x) | (f2b(v.y) << 16);
        unsigned int p1 = f2b(v.z) | (f2b(v.w) << 16);
        uint2 pk = make_uint2(p0, p1);
        *(uint2*)(xb + (size_t)n * D + c) = pk;
        *(uint2*)(A + (size_t)n * KTOT + KREL + c) = pk;
    } else if (blockIdx.x < (unsigned)(xb_blocks + bt_blocks)) {
        int idx = (blockIdx.x - xb_blocks) * 256 + threadIdx.x;
        if (idx >= 128 * KTOT) return;
        int o = idx / KTOT;
        int k = idx - o * KTOT;
        float v = (k < KREL) ? W_rel[(size_t)k * D + o]   // [r][d][o] flat = k*128+o
                             : W_self[(size_t)o * D + (k - KREL)];
        Bt[idx] = (unsigned short)f2b(v);
    } else {
        int idx = (blockIdx.x - xb_blocks - bt_blocks) * 256 + threadIdx.x;
        if (idx < Nn) hist[idx] = 0;
    }
}

// ---------- hist: per-dst counts ----------
__global__ void hist_kernel(const int* __restrict__ ei, int* __restrict__ hist, int E) {
    int e = blockIdx.x * 256 + threadIdx.x;
    if (e >= E) return;
    atomicAdd(hist + ei[E + e], 1);
}

// ---------- scan1: per-chunk (1024) sums ----------
__global__ void scan1_kernel(const int* __restrict__ hist, int* __restrict__ bsum, int nb) {
    __shared__ int red[256];
    int t = threadIdx.x;
    int base = blockIdx.x * 1024 + t * 4;
    int s = 0;
#pragma unroll
    for (int i = 0; i < 4; ++i) if (base + i < nb) s += hist[base + i];
    red[t] = s;
    __syncthreads();
    for (int off = 128; off > 0; off >>= 1) {
        if (t < off) red[t] += red[t + off];
        __syncthreads();
    }
    if (t == 0) bsum[blockIdx.x] = red[0];
}

// ---------- scan3: per-block bsum-prefix reduce + chunk exclusive scan ----------
__global__ void scan3_kernel(const int* __restrict__ hist, const int* __restrict__ bsum,
                             int* __restrict__ offsets, int* __restrict__ cursor,
                             int nb, int nparts, int E) {
    __shared__ int red[256];
    int t = threadIdx.x;
    // base = sum of bsum[i] for i < blockIdx.x  (reduction, nparts <= 256)
    red[t] = (t < nparts && t < (int)blockIdx.x) ? bsum[t] : 0;
    __syncthreads();
    for (int off = 128; off > 0; off >>= 1) {
        if (t < off) red[t] += red[t + off];
        __syncthreads();
    }
    int blockbase = red[0];
    __syncthreads();

    int base = blockIdx.x * 1024 + t * 4;
    int v[4]; int s = 0;
#pragma unroll
    for (int i = 0; i < 4; ++i) { v[i] = (base + i < nb) ? hist[base + i] : 0; s += v[i]; }
    red[t] = s;
    __syncthreads();
    for (int off = 1; off < 256; off <<= 1) {       // Hillis-Steele inclusive
        int u = (t >= off) ? red[t - off] : 0;
        __syncthreads();
        red[t] += u;
        __syncthreads();
    }
    int p = blockbase + red[t] - s;                 // exclusive prefix
#pragma unroll
    for (int i = 0; i < 4; ++i) {
        if (base + i < nb) { offsets[base + i] = p; cursor[base + i] = p; }
        p += v[i];
    }
    if (blockIdx.x == 0 && t == 0) offsets[nb] = E;  // sentinel
}

// ---------- reorder: pack src|rel, grouped by dst ----------
__global__ void reorder_kernel(const int* __restrict__ ei, const int* __restrict__ et,
                               int* __restrict__ cursor, int* __restrict__ sorted, int E) {
    int e = blockIdx.x * 256 + threadIdx.x;
    if (e >= E) return;
    int dst = ei[E + e];
    int pos = atomicAdd(cursor + dst, 1);
    sorted[pos] = ei[e] | (et[e] << 28);
}

// ---------- aggregation: one wave per node, scalar edge stream, 16 deep ----------
__global__ __launch_bounds__(256) void aggregate_kernel(
        const unsigned short* __restrict__ xb,
        const int* __restrict__ offsets,      // Nn+1, sentinel = E
        const int* __restrict__ sorted,       // src | rel<<28
        unsigned short* __restrict__ A,
        int Nn) {
    int node = blockIdx.x * 4 + (threadIdx.x >> 6);
    if (node >= Nn) return;
    int lane = threadIdx.x & 63;
    int laneoff = lane * 2;   // bf16-element offset within row

    // wave-uniform SGPR bounds -> uniform loop -> scalar-friendly loads
    int b0 = __builtin_amdgcn_readfirstlane(offsets[node]);
    int b1 = __builtin_amdgcn_readfirstlane(offsets[node + 1]);

    float accx[RNUM] = {0.f, 0.f, 0.f, 0.f, 0.f, 0.f, 0.f, 0.f};
    float accy[RNUM] = {0.f, 0.f, 0.f, 0.f, 0.f, 0.f, 0.f, 0.f};

    int e = b0;
    for (; e + 16 <= b1; e += 16) {
        int pv[16];
#pragma unroll
        for (int j = 0; j < 16; ++j)
            pv[j] = __builtin_amdgcn_readfirstlane(sorted[e + j]);   // SGPR
        unsigned int u[16];
#pragma unroll
        for (int j = 0; j < 16; ++j)
            u[j] = *(const unsigned int*)(xb + (size_t)(pv[j] & 0x0FFFFFFF) * D + laneoff);
#pragma unroll
        for (int j = 0; j < 16; ++j) {
            int r = ((unsigned)pv[j]) >> 28;          // SGPR -> uniform switch
            float lx = b2f_lo(u[j]), ly = b2f_hi(u[j]);
            switch (r) {
                case 0: accx[0] += lx; accy[0] += ly; break;
                case 1: accx[1] += lx; accy[1] += ly; break;
                case 2: accx[2] += lx; accy[2] += ly; break;
                case 3: accx[3] += lx; accy[3] += ly; break;
                case 4: accx[4] += lx; accy[4] += ly; break;
                case 5: accx[5] += lx; accy[5] += ly; break;
                case 6: accx[6] += lx; accy[6] += ly; break;
                default: accx[7] += lx; accy[7] += ly; break;
            }
        }
    }
    for (; e < b1; ++e) {
        int pv = __builtin_amdgcn_readfirstlane(sorted[e]);
        unsigned int u = *(const unsigned int*)(xb + (size_t)(pv & 0x0FFFFFFF) * D + laneoff);
        int r = ((unsigned)pv) >> 28;
        float lx = b2f_lo(u), ly = b2f_hi(u);
        switch (r) {
            case 0: accx[0] += lx; accy[0] += ly; break;
            case 1: accx[1] += lx; accy[1] += ly; break;
            case 2: accx[2] += lx; accy[2] += ly; break;
            case 3: accx[3] += lx; accy[3] += ly; break;
            case 4: accx[4] += lx; accy[4] += ly; break;
            case 5: accx[5] += lx; accy[5] += ly; break;
            case 6: accx[6] += lx; accy[6] += ly; break;
            default: accx[7] += lx; accy[7] += ly; break;
        }
    }

    float inv = 1.0f / fmaxf((float)(b1 - b0), 1.0f);
#pragma unroll
    for (int r = 0; r < RNUM; ++r) {
        unsigned int pk = f2b(accx[r] * inv) | (f2b(accy[r] * inv) << 16);
        *(unsigned int*)(A + (size_t)node * KTOT + r * D + laneoff) = pk;
    }
}

// ---------- GEMM: 128x128 tile, 4 waves x (64x64), m97 pattern ----------
__global__ __launch_bounds__(256) void gemm_kernel(
        const unsigned short* __restrict__ A,
        const unsigned short* __restrict__ Bt,
        const float* __restrict__ bias,
        float* __restrict__ out,
        int Nn) {
    __shared__ unsigned short As[BLK_M * 32];    // 128 rows x 32 k = 8 KB
    __shared__ unsigned short Bs[128 * 32];

    const int tid  = threadIdx.x;
    const int lane = tid & 63;
    const int w    = tid >> 6;
    const int wm   = w & 1;        // 2 m-slots of 64 rows
    const int wn   = w >> 1;       // 2 n-slots of 64 cols
    const int l16  = lane & 15;
    const int q    = lane >> 4;
    const int row0 = blockIdx.x * BLK_M;

    float4v acc[4][4] = {};

    // staging addresses: lane i -> row chunk (i/4), 16B piece (i%4)
    const int sr = lane >> 2;          // 0..15
    const int sc = (lane & 3) * 8;     // bf16 elems: 0,8,16,24

    for (int kk = 0; kk < KTOT; kk += 32) {
        // A: wave w stages rows w*32 + p*16, p in {0,1} (16 rows / instr)
#pragma unroll
        for (int p = 0; p < 2; ++p) {
            int r = w * 32 + p * 16 + sr;
            const unsigned short* g = A + (size_t)(row0 + r) * KTOT + kk + sc;
            gl_lds16(g, &As[(w * 2 + p) * 512]);
        }
        // B: same pattern over Bt's 128 rows (output cols)
#pragma unroll
        for (int p = 0; p < 2; ++p) {
            int r = w * 32 + p * 16 + sr;
            const unsigned short* g = Bt + (size_t)r * KTOT + kk + sc;
            gl_lds16(g, &Bs[(w * 2 + p) * 512]);
        }
        __syncthreads();

        short8 a[4], b[4];
#pragma unroll
        for (int mi = 0; mi < 4; ++mi)
            a[mi] = *reinterpret_cast<const short8*>(&As[(wm * 64 + mi * 16 + l16) * 32 + q * 8]);
#pragma unroll
        for (int ni = 0; ni < 4; ++ni)
            b[ni] = *reinterpret_cast<const short8*>(&Bs[(wn * 64 + ni * 16 + l16) * 32 + q * 8]);
#pragma unroll
        for (int mi = 0; mi < 4; ++mi)
#pragma unroll
            for (int ni = 0; ni < 4; ++ni)
                acc[mi][ni] = __builtin_amdgcn_mfma_f32_16x16x32_bf16(a[mi], b[ni], acc[mi][ni], 0, 0, 0);
        __syncthreads();
    }

#pragma unroll
    for (int ni = 0; ni < 4; ++ni) {
        int c = wn * 64 + ni * 16 + l16;
        float bv = bias[c];
#pragma unroll
        for (int mi = 0; mi < 4; ++mi) {
#pragma unroll
            for (int j = 0; j < 4; ++j) {
                int gr = row0 + wm * 64 + mi * 16 + q * 4 + j;
                if (gr < Nn)
                    out[(size_t)gr * D + c] = fmaxf(acc[mi][ni][j] + bv, 0.0f);
            }
        }
    }
}

extern "C" void kernel_launch(void* const* d_in, const int* in_sizes, int n_in,
                              void* d_out, int out_size, void* d_ws, size_t ws_size,
                              hipStream_t stream) {
    const float* x      = (const float*)d_in[0];
    const float* W_rel  = (const float*)d_in[1];
    const float* W_self = (const float*)d_in[2];
    const float* W_bias = (const float*)d_in[3];
    const int*   ei     = (const int*)d_in[4];
    const int*   et     = (const int*)d_in[5];

    const int Nn = in_sizes[0] / D;       // 50000
    const int E  = in_sizes[4] / 2;       // 800000
    const int nparts = (Nn + 1023) / 1024;                // 49
    const int npad = ((Nn + BLK_M - 1) / BLK_M) * BLK_M;  // pad rows for staging loads

    // ---- workspace layout (256B aligned chunks) ----
    char* p = (char*)d_ws;
    auto take = [&](size_t bytes) { char* q = p; p += (bytes + 255) & ~(size_t)255; return q; };
    unsigned short* A    = (unsigned short*)take((size_t)npad * KTOT * sizeof(unsigned short));
    unsigned short* xb   = (unsigned short*)take((size_t)Nn * D * sizeof(unsigned short));
    unsigned short* Bt   = (unsigned short*)take((size_t)128 * KTOT * sizeof(unsigned short));
    int* hist    = (int*)take((size_t)Nn * sizeof(int));
    int* offsets = (int*)take((size_t)(Nn + 1) * sizeof(int));
    int* cursor  = (int*)take((size_t)Nn * sizeof(int));
    int* bsum    = (int*)take(1024 * sizeof(int));
    int* sorted  = (int*)take((size_t)E * sizeof(int));

    const int xb_blocks = (Nn * 32 + 255) / 256;
    const int bt_blocks = (128 * KTOT + 255) / 256;
    const int hz_blocks = (Nn + 255) / 256;
    prep_kernel<<<xb_blocks + bt_blocks + hz_blocks, 256, 0, stream>>>(
        x, W_rel, W_self, xb, A, Bt, hist, Nn, xb_blocks, bt_blocks);
    hist_kernel<<<(E + 255) / 256, 256, 0, stream>>>(ei, hist, E);
    scan1_kernel<<<nparts, 256, 0, stream>>>(hist, bsum, Nn);
    scan3_kernel<<<nparts, 256, 0, stream>>>(hist, bsum, offsets, cursor, Nn, nparts, E);
    reorder_kernel<<<(E + 255) / 256, 256, 0, stream>>>(ei, et, cursor, sorted, E);
    aggregate_kernel<<<(Nn + 3) / 4, 256, 0, stream>>>(xb, offsets, sorted, A, Nn);
    gemm_kernel<<<npad / BLK_M, 256, 0, stream>>>(A, Bt, W_bias, (float*)d_out, Nn);
}

// Round 10
// 273.528 us; speedup vs baseline: 1.0631x; 1.0631x over previous
//
#include <hip/hip_runtime.h>
#include <hip/hip_bf16.h>

// RGCN layer: out = relu(x @ W_self^T + b + agg/deg)
// Pipeline v10 (7 dispatches, best-known config consolidated):
//   1. prep: xb = bf16(x), Bt = bf16([W_rel; W_self^T]), zero hist
//   2. hist: per-dst edge counts (50k bins, atomics)
//   3. scan1: per-1024-chunk sums -> bsum
//   4. scan3: block bsum-prefix reduce + chunk exclusive scan -> offsets/cursor
//   5. reorder: sorted[pos] = src | rel<<28
//   6. aggregate: one wave per node; SCALAR edge stream (R8), writes A (pitch 1024)
//   7. gemm: 64x128 tile (R8); self K-columns staged straight from xb (no A copy)

#define D 128
#define RNUM 8
#define KREL (RNUM * D)      // 1024 — also A's row pitch
#define KTOT (KREL + D)      // 1152
#define BLK_M 64

typedef short short8 __attribute__((ext_vector_type(8)));
typedef float float4v __attribute__((ext_vector_type(4)));

// fp32 -> bf16 round-nearest-even (bit pattern)
static __device__ __forceinline__ unsigned int f2b(float f) {
    unsigned int u = __float_as_uint(f);
    return (u + 0x7fffu + ((u >> 16) & 1u)) >> 16;
}
static __device__ __forceinline__ float b2f_lo(unsigned int u) {
    return __uint_as_float(u << 16);
}
static __device__ __forceinline__ float b2f_hi(unsigned int u) {
    return __uint_as_float(u & 0xffff0000u);
}

static __device__ __forceinline__ void gl_lds16(const void* g, void* l) {
    __builtin_amdgcn_global_load_lds(
        (const __attribute__((address_space(1))) unsigned int*)g,
        (__attribute__((address_space(3))) unsigned int*)l, 16, 0, 0);
}

// ---------- prep (3 block ranges): xb | Bt | hist zero ----------
__global__ void prep_kernel(const float* __restrict__ x,
                            const float* __restrict__ W_rel,
                            const float* __restrict__ W_self,
                            unsigned short* __restrict__ xb,
                            unsigned short* __restrict__ Bt,
                            int* __restrict__ hist,
                            int Nn, int xb_blocks, int bt_blocks) {
    if (blockIdx.x < (unsigned)xb_blocks) {
        int t = blockIdx.x * 256 + threadIdx.x;
        int n = t >> 5;              // 32 threads/row, 4 cols each
        int c = (t & 31) * 4;
        if (n >= Nn) return;
        float4 v = *(const float4*)(x + (size_t)n * D + c);
        unsigned int p0 = f2b(v.x) | (f2b(v.y) << 16);
        unsigned int p1 = f2b(v.z) | (f2b(v.w) << 16);
        *(uint2*)(xb + (size_t)n * D + c) = make_uint2(p0, p1);
    } else if (blockIdx.x < (unsigned)(xb_blocks + bt_blocks)) {
        int idx = (blockIdx.x - xb_blocks) * 256 + threadIdx.x;
        if (idx >= 128 * KTOT) return;
        int o = idx / KTOT;
        int k = idx - o * KTOT;
        float v = (k < KREL) ? W_rel[(size_t)k * D + o]   // [r][d][o] flat = k*128+o
                             : W_self[(size_t)o * D + (k - KREL)];
        Bt[idx] = (unsigned short)f2b(v);
    } else {
        int idx = (blockIdx.x - xb_blocks - bt_blocks) * 256 + threadIdx.x;
        if (idx < Nn) hist[idx] = 0;
    }
}

// ---------- hist: per-dst counts ----------
__global__ void hist_kernel(const int* __restrict__ ei, int* __restrict__ hist, int E) {
    int e = blockIdx.x * 256 + threadIdx.x;
    if (e >= E) return;
    atomicAdd(hist + ei[E + e], 1);
}

// ---------- scan1: per-chunk (1024) sums ----------
__global__ void scan1_kernel(const int* __restrict__ hist, int* __restrict__ bsum, int nb) {
    __shared__ int red[256];
    int t = threadIdx.x;
    int base = blockIdx.x * 1024 + t * 4;
    int s = 0;
#pragma unroll
    for (int i = 0; i < 4; ++i) if (base + i < nb) s += hist[base + i];
    red[t] = s;
    __syncthreads();
    for (int off = 128; off > 0; off >>= 1) {
        if (t < off) red[t] += red[t + off];
        __syncthreads();
    }
    if (t == 0) bsum[blockIdx.x] = red[0];
}

// ---------- scan3: per-block bsum-prefix reduce + chunk exclusive scan ----------
__global__ void scan3_kernel(const int* __restrict__ hist, const int* __restrict__ bsum,
                             int* __restrict__ offsets, int* __restrict__ cursor,
                             int nb, int nparts, int E) {
    __shared__ int red[256];
    int t = threadIdx.x;
    // base = sum of bsum[i] for i < blockIdx.x  (nparts <= 256)
    red[t] = (t < nparts && t < (int)blockIdx.x) ? bsum[t] : 0;
    __syncthreads();
    for (int off = 128; off > 0; off >>= 1) {
        if (t < off) red[t] += red[t + off];
        __syncthreads();
    }
    int blockbase = red[0];
    __syncthreads();

    int base = blockIdx.x * 1024 + t * 4;
    int v[4]; int s = 0;
#pragma unroll
    for (int i = 0; i < 4; ++i) { v[i] = (base + i < nb) ? hist[base + i] : 0; s += v[i]; }
    red[t] = s;
    __syncthreads();
    for (int off = 1; off < 256; off <<= 1) {       // Hillis-Steele inclusive
        int u = (t >= off) ? red[t - off] : 0;
        __syncthreads();
        red[t] += u;
        __syncthreads();
    }
    int p = blockbase + red[t] - s;                 // exclusive prefix
#pragma unroll
    for (int i = 0; i < 4; ++i) {
        if (base + i < nb) { offsets[base + i] = p; cursor[base + i] = p; }
        p += v[i];
    }
    if (blockIdx.x == 0 && t == 0) offsets[nb] = E;  // sentinel
}

// ---------- reorder: pack src|rel, grouped by dst ----------
__global__ void reorder_kernel(const int* __restrict__ ei, const int* __restrict__ et,
                               int* __restrict__ cursor, int* __restrict__ sorted, int E) {
    int e = blockIdx.x * 256 + threadIdx.x;
    if (e >= E) return;
    int dst = ei[E + e];
    int pos = atomicAdd(cursor + dst, 1);
    sorted[pos] = ei[e] | (et[e] << 28);
}

// ---------- aggregation: one wave per node, scalar edge stream (R8) ----------
__global__ __launch_bounds__(256) void aggregate_kernel(
        const unsigned short* __restrict__ xb,
        const int* __restrict__ offsets,      // Nn+1, sentinel = E
        const int* __restrict__ sorted,       // src | rel<<28
        unsigned short* __restrict__ A,       // [Nn][KREL]
        int Nn) {
    int node = blockIdx.x * 4 + (threadIdx.x >> 6);
    if (node >= Nn) return;
    int lane = threadIdx.x & 63;
    int laneoff = lane * 2;   // bf16-element offset within row

    // wave-uniform SGPR bounds -> uniform loop -> scalar loads of sorted[]
    int b0 = __builtin_amdgcn_readfirstlane(offsets[node]);
    int b1 = __builtin_amdgcn_readfirstlane(offsets[node + 1]);

    float accx[RNUM] = {0.f, 0.f, 0.f, 0.f, 0.f, 0.f, 0.f, 0.f};
    float accy[RNUM] = {0.f, 0.f, 0.f, 0.f, 0.f, 0.f, 0.f, 0.f};

    int e = b0;
    for (; e + 8 <= b1; e += 8) {
        int pv[8];
#pragma unroll
        for (int j = 0; j < 8; ++j)
            pv[j] = __builtin_amdgcn_readfirstlane(sorted[e + j]);   // SGPR
        unsigned int u[8];
#pragma unroll
        for (int j = 0; j < 8; ++j)
            u[j] = *(const unsigned int*)(xb + (size_t)(pv[j] & 0x0FFFFFFF) * D + laneoff);
#pragma unroll
        for (int j = 0; j < 8; ++j) {
            int r = ((unsigned)pv[j]) >> 28;          // SGPR -> uniform switch
            float lx = b2f_lo(u[j]), ly = b2f_hi(u[j]);
            switch (r) {
                case 0: accx[0] += lx; accy[0] += ly; break;
                case 1: accx[1] += lx; accy[1] += ly; break;
                case 2: accx[2] += lx; accy[2] += ly; break;
                case 3: accx[3] += lx; accy[3] += ly; break;
                case 4: accx[4] += lx; accy[4] += ly; break;
                case 5: accx[5] += lx; accy[5] += ly; break;
                case 6: accx[6] += lx; accy[6] += ly; break;
                default: accx[7] += lx; accy[7] += ly; break;
            }
        }
    }
    for (; e < b1; ++e) {
        int pv = __builtin_amdgcn_readfirstlane(sorted[e]);
        unsigned int u = *(const unsigned int*)(xb + (size_t)(pv & 0x0FFFFFFF) * D + laneoff);
        int r = ((unsigned)pv) >> 28;
        float lx = b2f_lo(u), ly = b2f_hi(u);
        switch (r) {
            case 0: accx[0] += lx; accy[0] += ly; break;
            case 1: accx[1] += lx; accy[1] += ly; break;
            case 2: accx[2] += lx; accy[2] += ly; break;
            case 3: accx[3] += lx; accy[3] += ly; break;
            case 4: accx[4] += lx; accy[4] += ly; break;
            case 5: accx[5] += lx; accy[5] += ly; break;
            case 6: accx[6] += lx; accy[6] += ly; break;
            default: accx[7] += lx; accy[7] += ly; break;
        }
    }

    float inv = 1.0f / fmaxf((float)(b1 - b0), 1.0f);
#pragma unroll
    for (int r = 0; r < RNUM; ++r) {
        unsigned int pk = f2b(accx[r] * inv) | (f2b(accy[r] * inv) << 16);
        *(unsigned int*)(A + (size_t)node * KREL + r * D + laneoff) = pk;
    }
}

// ---------- GEMM: out[64 x 128 tile] = relu([A|xb] @ Bt^T + b) ----------
__global__ __launch_bounds__(256) void gemm_kernel(
        const unsigned short* __restrict__ A,    // [.][KREL]
        const unsigned short* __restrict__ xb,   // [.][D] — self K-columns
        const unsigned short* __restrict__ Bt,
        const float* __restrict__ bias,
        float* __restrict__ out,
        int Nn) {
    __shared__ unsigned short As[BLK_M * 32];    // 64 rows x 32 k (no pad: global_load_lds)
    __shared__ unsigned short Bs[128 * 32];

    const int tid  = threadIdx.x;
    const int lane = tid & 63;
    const int w    = tid >> 6;
    const int wm   = w & 1;        // 2 m-slots of 32 rows
    const int wn   = w >> 1;       // 2 n-slots of 64 cols
    const int l16  = lane & 15;
    const int q    = lane >> 4;
    const int row0 = blockIdx.x * BLK_M;

    float4v acc[2][4] = {};

    // staging addresses: lane i -> row chunk (i/4), 16B piece (i%4)
    const int sr = lane >> 2;          // 0..15
    const int sc = (lane & 3) * 8;     // bf16 elems: 0,8,16,24

    for (int kk = 0; kk < KTOT; kk += 32) {
        // A tile source: rel part from A (pitch KREL); self part straight from xb (pitch D)
        const unsigned short* abase;
        size_t apitch; int kof;
        if (kk < KREL) { abase = A;  apitch = KREL; kof = kk; }
        else           { abase = xb; apitch = D;    kof = kk - KREL; }
        // A: wave w stages rows w*16 .. w*16+15 (1024B)
        {
            int r = w * 16 + sr;
            const unsigned short* g = abase + (size_t)(row0 + r) * apitch + kof + sc;
            gl_lds16(g, &As[w * 512]);
        }
        // B: wave w stages rows w*32+p*16, p in {0,1}
#pragma unroll
        for (int p = 0; p < 2; ++p) {
            int r = w * 32 + p * 16 + sr;
            const unsigned short* g = Bt + (size_t)r * KTOT + kk + sc;
            gl_lds16(g, &Bs[(w * 2 + p) * 512]);
        }
        __syncthreads();

        short8 a[2], b[4];
#pragma unroll
        for (int mi = 0; mi < 2; ++mi)
            a[mi] = *reinterpret_cast<const short8*>(&As[(wm * 32 + mi * 16 + l16) * 32 + q * 8]);
#pragma unroll
        for (int ni = 0; ni < 4; ++ni)
            b[ni] = *reinterpret_cast<const short8*>(&Bs[(wn * 64 + ni * 16 + l16) * 32 + q * 8]);
#pragma unroll
        for (int mi = 0; mi < 2; ++mi)
#pragma unroll
            for (int ni = 0; ni < 4; ++ni)
                acc[mi][ni] = __builtin_amdgcn_mfma_f32_16x16x32_bf16(a[mi], b[ni], acc[mi][ni], 0, 0, 0);
        __syncthreads();
    }

#pragma unroll
    for (int ni = 0; ni < 4; ++ni) {
        int c = wn * 64 + ni * 16 + l16;
        float bv = bias[c];
#pragma unroll
        for (int mi = 0; mi < 2; ++mi) {
#pragma unroll
            for (int j = 0; j < 4; ++j) {
                int gr = row0 + wm * 32 + mi * 16 + q * 4 + j;
                if (gr < Nn)
                    out[(size_t)gr * D + c] = fmaxf(acc[mi][ni][j] + bv, 0.0f);
            }
        }
    }
}

extern "C" void kernel_launch(void* const* d_in, const int* in_sizes, int n_in,
                              void* d_out, int out_size, void* d_ws, size_t ws_size,
                              hipStream_t stream) {
    const float* x      = (const float*)d_in[0];
    const float* W_rel  = (const float*)d_in[1];
    const float* W_self = (const float*)d_in[2];
    const float* W_bias = (const float*)d_in[3];
    const int*   ei     = (const int*)d_in[4];
    const int*   et     = (const int*)d_in[5];

    const int Nn = in_sizes[0] / D;       // 50000
    const int E  = in_sizes[4] / 2;       // 800000
    const int nparts = (Nn + 1023) / 1024;                // 49
    const int npad = ((Nn + BLK_M - 1) / BLK_M) * BLK_M;  // pad rows for staging loads

    // ---- workspace layout (256B aligned chunks) ----
    char* p = (char*)d_ws;
    auto take = [&](size_t bytes) { char* q = p; p += (bytes + 255) & ~(size_t)255; return q; };
    unsigned short* A    = (unsigned short*)take((size_t)npad * KREL * sizeof(unsigned short));
    unsigned short* xb   = (unsigned short*)take((size_t)npad * D * sizeof(unsigned short));
    unsigned short* Bt   = (unsigned short*)take((size_t)128 * KTOT * sizeof(unsigned short));
    int* hist    = (int*)take((size_t)Nn * sizeof(int));
    int* offsets = (int*)take((size_t)(Nn + 1) * sizeof(int));
    int* cursor  = (int*)take((size_t)Nn * sizeof(int));
    int* bsum    = (int*)take(1024 * sizeof(int));
    int* sorted  = (int*)take((size_t)E * sizeof(int));

    const int xb_blocks = (Nn * 32 + 255) / 256;
    const int bt_blocks = (128 * KTOT + 255) / 256;
    const int hz_blocks = (Nn + 255) / 256;
    prep_kernel<<<xb_blocks + bt_blocks + hz_blocks, 256, 0, stream>>>(
        x, W_rel, W_self, xb, Bt, hist, Nn, xb_blocks, bt_blocks);
    hist_kernel<<<(E + 255) / 256, 256, 0, stream>>>(ei, hist, E);
    scan1_kernel<<<nparts, 256, 0, stream>>>(hist, bsum, Nn);
    scan3_kernel<<<nparts, 256, 0, stream>>>(hist, bsum, offsets, cursor, Nn, nparts, E);
    reorder_kernel<<<(E + 255) / 256, 256, 0, stream>>>(ei, et, cursor, sorted, E);
    aggregate_kernel<<<(Nn + 3) / 4, 256, 0, stream>>>(xb, offsets, sorted, A, Nn);
    gemm_kernel<<<npad / BLK_M, 256, 0, stream>>>(A, xb, Bt, W_bias, (float*)d_out, Nn);
}